// Round 1
// baseline (1283.736 us; speedup 1.0000x reference)
//
#include <hip/hip_runtime.h>

#define NF 40
#define H  64
#define NC 3

// --- degree init: deg[i] = 1 (self-loop) ---
__global__ void k_init_deg(float* __restrict__ deg, int n) {
    int i = blockIdx.x * blockDim.x + threadIdx.x;
    if (i < n) deg[i] = 1.0f;
}

// --- deg[dst] += 1 per edge ---
__global__ void k_degree(const int* __restrict__ dst, float* __restrict__ deg, int ne) {
    int i = blockIdx.x * blockDim.x + threadIdx.x;
    int stride = gridDim.x * blockDim.x;
    for (; i < ne; i += stride) atomicAdd(&deg[dst[i]], 1.0f);
}

// --- deg -> rsqrt(deg) in place ---
__global__ void k_rsqrt(float* __restrict__ deg, int n) {
    int i = blockIdx.x * blockDim.x + threadIdx.x;
    if (i < n) deg[i] = rsqrtf(deg[i]);
}

// --- ax[n][f] = x[n][f] * dinv[n]^2  (self-loop term = non-atomic init) ---
__global__ void k_ax_init(const float* __restrict__ x, const float* __restrict__ dinv,
                          float* __restrict__ ax, int total) {
    int i = blockIdx.x * blockDim.x + threadIdx.x;
    if (i < total) {
        int node = i / NF;
        float di = dinv[node];
        ax[i] = x[i] * di * di;
    }
}

// --- edge aggregation in X-domain: ax[d] += x[s] * dinv[s]*dinv[d]; one wave per edge ---
__global__ void k_agg_x(const int* __restrict__ src, const int* __restrict__ dst,
                        const float* __restrict__ dinv, const float* __restrict__ x,
                        float* __restrict__ ax, int ne) {
    int lane = threadIdx.x & 63;
    long wid = (long)blockIdx.x * (blockDim.x >> 6) + (threadIdx.x >> 6);
    long nw  = (long)gridDim.x * (blockDim.x >> 6);
    for (long e = wid; e < ne; e += nw) {
        int s = src[e], d = dst[e];
        float nrm = dinv[s] * dinv[d];
        if (lane < NF) {
            atomicAdd(&ax[(long)d * NF + lane], x[(long)s * NF + lane] * nrm);
        }
    }
}

// --- fused per-node: h=relu(ax·W1+b1); spike=(h·Wf+bf>=0.5); s2=spike·W2;
//     also init out with self-loop term s2*dinv^2 ---
__global__ __launch_bounds__(256) void k_node(
        const float* __restrict__ ax,
        const float* __restrict__ W1, const float* __restrict__ b1,
        const float* __restrict__ Wf, const float* __restrict__ bf,
        const float* __restrict__ W2, const float* __restrict__ dinv,
        float* __restrict__ s2, float* __restrict__ out, int n) {
    __shared__ float lW1[NF * H];
    __shared__ float lWf[H * H];
    __shared__ float lW2[H * NC];
    __shared__ float lb1[H];
    __shared__ float lbf[H];
    __shared__ float lax[4][NF];
    __shared__ float lh[4][H];
    int t = threadIdx.x;
    for (int i = t; i < NF * H; i += 256) lW1[i] = W1[i];
    for (int i = t; i < H * H;  i += 256) lWf[i] = Wf[i];
    if (t < H * NC) lW2[t] = W2[t];
    if (t < H) { lb1[t] = b1[t]; lbf[t] = bf[t]; }
    __syncthreads();

    int w = t >> 6, lane = t & 63;
    int node = blockIdx.x * 4 + w;
    if (node >= n) return;

    if (lane < NF) lax[w][lane] = ax[node * NF + lane];
    // same-wave LDS RAW: compiler inserts lgkmcnt waits; no block barrier needed
    float acc = lb1[lane];
    #pragma unroll
    for (int k = 0; k < NF; ++k) acc += lax[w][k] * lW1[k * H + lane];
    float h = fmaxf(acc, 0.0f);
    lh[w][lane] = h;

    float mem = lbf[lane];
    #pragma unroll
    for (int k = 0; k < H; ++k) mem += lh[w][k] * lWf[k * H + lane];
    float spike = (mem >= 0.5f) ? 1.0f : 0.0f;

    float v0 = spike * lW2[lane * NC + 0];
    float v1 = spike * lW2[lane * NC + 1];
    float v2 = spike * lW2[lane * NC + 2];
    for (int off = 32; off; off >>= 1) {
        v0 += __shfl_down(v0, off);
        v1 += __shfl_down(v1, off);
        v2 += __shfl_down(v2, off);
    }
    if (lane == 0) {
        float di = dinv[node], dd = di * di;
        s2[node * NC + 0] = v0;
        s2[node * NC + 1] = v1;
        s2[node * NC + 2] = v2;
        out[node * NC + 0] = v0 * dd;   // self-loop init of conv2 accumulator
        out[node * NC + 1] = v1 * dd;
        out[node * NC + 2] = v2 * dd;
    }
}

// --- edge aggregation of s2 (3 features), one thread per edge ---
__global__ void k_agg2(const int* __restrict__ src, const int* __restrict__ dst,
                       const float* __restrict__ dinv, const float* __restrict__ s2,
                       float* __restrict__ out, int ne) {
    int i = blockIdx.x * blockDim.x + threadIdx.x;
    int stride = gridDim.x * blockDim.x;
    for (; i < ne; i += stride) {
        int s = src[i], d = dst[i];
        float nrm = dinv[s] * dinv[d];
        atomicAdd(&out[d * NC + 0], s2[s * NC + 0] * nrm);
        atomicAdd(&out[d * NC + 1], s2[s * NC + 1] * nrm);
        atomicAdd(&out[d * NC + 2], s2[s * NC + 2] * nrm);
    }
}

// --- out = (out + b2) * ethical_filter ---
__global__ void k_final(float* __restrict__ out, const float* __restrict__ b2,
                        const float* __restrict__ ef, int total) {
    int i = blockIdx.x * blockDim.x + threadIdx.x;
    if (i < total) {
        int c = i % NC;
        out[i] = (out[i] + b2[c]) * ef[c];
    }
}

extern "C" void kernel_launch(void* const* d_in, const int* in_sizes, int n_in,
                              void* d_out, int out_size, void* d_ws, size_t ws_size,
                              hipStream_t stream) {
    const float* x  = (const float*)d_in[0];
    const int*   ei = (const int*)d_in[1];
    const float* W1 = (const float*)d_in[2];
    const float* b1 = (const float*)d_in[3];
    const float* Wf = (const float*)d_in[4];
    const float* bf = (const float*)d_in[5];
    const float* W2 = (const float*)d_in[6];
    const float* b2 = (const float*)d_in[7];
    const float* ef = (const float*)d_in[8];

    int n  = in_sizes[0] / NF;
    int ne = in_sizes[1] / 2;
    const int* src = ei;
    const int* dst = ei + ne;

    char* ws = (char*)d_ws;
    float* deg = (float*)ws;                                          // n floats
    size_t off = ((size_t)n * 4 + 255) & ~(size_t)255;
    float* ax  = (float*)(ws + off);                                  // n*NF floats
    off += (((size_t)n * NF * 4 + 255) & ~(size_t)255);
    float* s2  = (float*)(ws + off);                                  // n*NC floats
    float* out = (float*)d_out;

    k_init_deg<<<(n + 255) / 256, 256, 0, stream>>>(deg, n);
    k_degree  <<<2048, 256, 0, stream>>>(dst, deg, ne);
    k_rsqrt   <<<(n + 255) / 256, 256, 0, stream>>>(deg, n);
    k_ax_init <<<(n * NF + 255) / 256, 256, 0, stream>>>(x, deg, ax, n * NF);
    k_agg_x   <<<2048, 256, 0, stream>>>(src, dst, deg, x, ax, ne);
    k_node    <<<(n + 3) / 4, 256, 0, stream>>>(ax, W1, b1, Wf, bf, W2, deg, s2, out, n);
    k_agg2    <<<2048, 256, 0, stream>>>(src, dst, deg, s2, out, ne);
    k_final   <<<(n * NC + 255) / 256, 256, 0, stream>>>(out, b2, ef, n * NC);
}

// Round 2
// 734.364 us; speedup vs baseline: 1.7481x; 1.7481x over previous
//
#include <hip/hip_runtime.h>

#define NF 40
#define H  64
#define NC 3
#define SCANB 512   // max blocks for single-block scan (NB=391 fits)

// --- zero int array ---
__global__ void k_zero(int* __restrict__ p, int n) {
    int i = blockIdx.x * blockDim.x + threadIdx.x;
    if (i < n) p[i] = 0;
}

// --- count[dst] += 1 per edge ---
__global__ void k_count(const int* __restrict__ dst, int* __restrict__ count, int ne) {
    int i = blockIdx.x * blockDim.x + threadIdx.x;
    int stride = gridDim.x * blockDim.x;
    for (; i < ne; i += stride) atomicAdd(&count[dst[i]], 1);
}

// --- per-block sums of count ---
__global__ void k_bsum(const int* __restrict__ count, int* __restrict__ bsum, int n) {
    __shared__ int s[256];
    int t = threadIdx.x;
    int i = blockIdx.x * 256 + t;
    s[t] = (i < n) ? count[i] : 0;
    __syncthreads();
    for (int off = 128; off; off >>= 1) {
        if (t < off) s[t] += s[t + off];
        __syncthreads();
    }
    if (t == 0) bsum[blockIdx.x] = s[0];
}

// --- single-block exclusive scan of block sums ---
__global__ void k_scanb(const int* __restrict__ bsum, int* __restrict__ boff, int nb) {
    __shared__ int s[SCANB];
    int t = threadIdx.x;
    int v = (t < nb) ? bsum[t] : 0;
    s[t] = v;
    __syncthreads();
    for (int off = 1; off < SCANB; off <<= 1) {
        int a = (t >= off) ? s[t - off] : 0;
        __syncthreads();
        s[t] += a;
        __syncthreads();
    }
    if (t < nb) boff[t] = s[t] - v;   // exclusive
}

// --- row_start / cursor / dinv from counts + block offsets ---
__global__ void k_starts(const int* __restrict__ count, const int* __restrict__ boff,
                         int* __restrict__ row_start, int* __restrict__ cursor,
                         float* __restrict__ dinv, int n, int ne) {
    __shared__ int s[256];
    int t = threadIdx.x;
    int i = blockIdx.x * 256 + t;
    int v = (i < n) ? count[i] : 0;
    s[t] = v;
    __syncthreads();
    for (int off = 1; off < 256; off <<= 1) {
        int a = (t >= off) ? s[t - off] : 0;
        __syncthreads();
        s[t] += a;
        __syncthreads();
    }
    if (i < n) {
        int start = boff[blockIdx.x] + s[t] - v;   // exclusive within block + block base
        row_start[i] = start;
        cursor[i] = start;
        dinv[i] = rsqrtf((float)(v + 1));          // +1 self-loop
    }
    if (blockIdx.x == 0 && t == 0) row_start[n] = ne;
}

// --- scatter edges into CSR buckets by dst ---
__global__ void k_scatter(const int* __restrict__ src, const int* __restrict__ dst,
                          int* __restrict__ cursor, int* __restrict__ csr, int ne) {
    int i = blockIdx.x * blockDim.x + threadIdx.x;
    int stride = gridDim.x * blockDim.x;
    for (; i < ne; i += stride) {
        int pos = atomicAdd(&cursor[dst[i]], 1);
        csr[pos] = src[i];
    }
}

// --- pull-aggregate conv1 input: ax[d] = dinv[d]*(sum_s x[s]*dinv[s] + x[d]*dinv[d]) ---
__global__ __launch_bounds__(256) void k_pull1(
        const int* __restrict__ row_start, const int* __restrict__ csr,
        const float* __restrict__ dinv, const float* __restrict__ x,
        float* __restrict__ ax, int n) {
    int w = threadIdx.x >> 6, lane = threadIdx.x & 63;
    int d = blockIdx.x * 4 + w;
    if (d >= n) return;
    int beg = row_start[d], end = row_start[d + 1];
    float dd = dinv[d];
    float acc = 0.0f;
    if (lane < NF) acc = x[d * NF + lane] * dd;    // self-loop term x[d]*dinv[d]
    int j = beg;
    for (; j + 1 < end; j += 2) {                  // unroll 2 for independent gathers
        int s0 = csr[j], s1 = csr[j + 1];
        float n0 = dinv[s0], n1 = dinv[s1];
        if (lane < NF) {
            acc += x[s0 * NF + lane] * n0;
            acc += x[s1 * NF + lane] * n1;
        }
    }
    if (j < end) {
        int s0 = csr[j];
        float n0 = dinv[s0];
        if (lane < NF) acc += x[s0 * NF + lane] * n0;
    }
    if (lane < NF) ax[d * NF + lane] = acc * dd;
}

// --- fused per-node MLP: h=relu(ax·W1+b1); spike=(h·Wf+bf>=0.5); s2s=spike·W2·dinv ---
__global__ __launch_bounds__(256) void k_node(
        const float* __restrict__ ax,
        const float* __restrict__ W1, const float* __restrict__ b1,
        const float* __restrict__ Wf, const float* __restrict__ bf,
        const float* __restrict__ W2, const float* __restrict__ dinv,
        float* __restrict__ s2s, int n) {
    __shared__ float lW1[NF * H];
    __shared__ float lWf[H * H];
    __shared__ float lW2[H * NC];
    __shared__ float lb1[H];
    __shared__ float lbf[H];
    __shared__ float lax[4][NF];
    __shared__ float lh[4][H];
    int t = threadIdx.x;
    for (int i = t; i < NF * H; i += 256) lW1[i] = W1[i];
    for (int i = t; i < H * H;  i += 256) lWf[i] = Wf[i];
    if (t < H * NC) lW2[t] = W2[t];
    if (t < H) { lb1[t] = b1[t]; lbf[t] = bf[t]; }
    __syncthreads();

    int w = t >> 6, lane = t & 63;
    // 8 nodes per wave, 32 per block: amortize weight staging
    for (int it = 0; it < 8; ++it) {
        int node = blockIdx.x * 32 + w * 8 + it;
        if (node >= n) break;

        if (lane < NF) lax[w][lane] = ax[node * NF + lane];
        float acc = lb1[lane];
        #pragma unroll
        for (int k = 0; k < NF; ++k) acc += lax[w][k] * lW1[k * H + lane];
        float h = fmaxf(acc, 0.0f);
        lh[w][lane] = h;

        float mem = lbf[lane];
        #pragma unroll
        for (int k = 0; k < H; ++k) mem += lh[w][k] * lWf[k * H + lane];
        float spike = (mem >= 0.5f) ? 1.0f : 0.0f;

        float v0 = spike * lW2[lane * NC + 0];
        float v1 = spike * lW2[lane * NC + 1];
        float v2 = spike * lW2[lane * NC + 2];
        for (int off = 32; off; off >>= 1) {
            v0 += __shfl_down(v0, off);
            v1 += __shfl_down(v1, off);
            v2 += __shfl_down(v2, off);
        }
        if (lane == 0) {
            float di = dinv[node];
            s2s[node * NC + 0] = v0 * di;
            s2s[node * NC + 1] = v1 * di;
            s2s[node * NC + 2] = v2 * di;
        }
    }
}

// --- pull-aggregate conv2 + bias + filter: out[d]=(dinv[d]*(sum s2s[s] + s2s[d]) + b2)*ef ---
__global__ __launch_bounds__(256) void k_pull2(
        const int* __restrict__ row_start, const int* __restrict__ csr,
        const float* __restrict__ dinv, const float* __restrict__ s2s,
        const float* __restrict__ b2, const float* __restrict__ ef,
        float* __restrict__ out, int n) {
    int w = threadIdx.x >> 6, lane = threadIdx.x & 63;
    int d = blockIdx.x * 4 + w;
    if (d >= n) return;
    int beg = row_start[d], end = row_start[d + 1];
    float a0 = 0.0f, a1 = 0.0f, a2 = 0.0f;
    for (int j = beg + lane; j < end; j += 64) {
        int s = csr[j];
        a0 += s2s[s * NC + 0];
        a1 += s2s[s * NC + 1];
        a2 += s2s[s * NC + 2];
    }
    for (int off = 32; off; off >>= 1) {
        a0 += __shfl_down(a0, off);
        a1 += __shfl_down(a1, off);
        a2 += __shfl_down(a2, off);
    }
    if (lane == 0) {
        float dd = dinv[d];
        out[d * NC + 0] = (dd * (a0 + s2s[d * NC + 0]) + b2[0]) * ef[0];
        out[d * NC + 1] = (dd * (a1 + s2s[d * NC + 1]) + b2[1]) * ef[1];
        out[d * NC + 2] = (dd * (a2 + s2s[d * NC + 2]) + b2[2]) * ef[2];
    }
}

extern "C" void kernel_launch(void* const* d_in, const int* in_sizes, int n_in,
                              void* d_out, int out_size, void* d_ws, size_t ws_size,
                              hipStream_t stream) {
    const float* x  = (const float*)d_in[0];
    const int*   ei = (const int*)d_in[1];
    const float* W1 = (const float*)d_in[2];
    const float* b1 = (const float*)d_in[3];
    const float* Wf = (const float*)d_in[4];
    const float* bf = (const float*)d_in[5];
    const float* W2 = (const float*)d_in[6];
    const float* b2 = (const float*)d_in[7];
    const float* ef = (const float*)d_in[8];

    int n  = in_sizes[0] / NF;
    int ne = in_sizes[1] / 2;
    const int* src = ei;
    const int* dst = ei + ne;
    int nb = (n + 255) / 256;

    auto al = [](size_t v) { return (v + 255) & ~(size_t)255; };
    char* ws = (char*)d_ws;
    size_t off = 0;
    int*   count     = (int*)(ws + off);  off += al((size_t)n * 4);
    int*   row_start = (int*)(ws + off);  off += al(((size_t)n + 1) * 4);
    int*   cursor    = (int*)(ws + off);  off += al((size_t)n * 4);
    float* dinv      = (float*)(ws + off); off += al((size_t)n * 4);
    int*   bsum      = (int*)(ws + off);  off += al((size_t)SCANB * 4);
    int*   boff      = (int*)(ws + off);  off += al((size_t)SCANB * 4);
    int*   csr       = (int*)(ws + off);  off += al((size_t)ne * 4);
    float* ax        = (float*)(ws + off); off += al((size_t)n * NF * 4);
    float* s2s       = (float*)(ws + off); off += al((size_t)n * NC * 4);
    float* out = (float*)d_out;

    k_zero   <<<nb, 256, 0, stream>>>(count, n);
    k_count  <<<1024, 256, 0, stream>>>(dst, count, ne);
    k_bsum   <<<nb, 256, 0, stream>>>(count, bsum, n);
    k_scanb  <<<1, SCANB, 0, stream>>>(bsum, boff, nb);
    k_starts <<<nb, 256, 0, stream>>>(count, boff, row_start, cursor, dinv, n, ne);
    k_scatter<<<1024, 256, 0, stream>>>(src, dst, cursor, csr, ne);
    k_pull1  <<<(n + 3) / 4, 256, 0, stream>>>(row_start, csr, dinv, x, ax, n);
    k_node   <<<(n + 31) / 32, 256, 0, stream>>>(ax, W1, b1, Wf, bf, W2, dinv, s2s, n);
    k_pull2  <<<(n + 3) / 4, 256, 0, stream>>>(row_start, csr, dinv, s2s, b2, ef, out, n);
}

// Round 3
// 341.378 us; speedup vs baseline: 3.7604x; 2.1512x over previous
//
#include <hip/hip_runtime.h>

#define NF 40
#define NF4 10
#define H  64
#define NC 3
#define MAXNBK 512   // buckets = ceil(n/256); 391 for n=100000

// --- zero ints ---
__global__ void k_zero(int* __restrict__ p, int n) {
    int i = blockIdx.x * blockDim.x + threadIdx.x;
    if (i < n) p[i] = 0;
}

// --- bucket histogram: LDS-aggregated, one global atomic per (block,bucket) ---
__global__ __launch_bounds__(256) void k_binhist(const int* __restrict__ dst,
                                                 int* __restrict__ gbcnt, int ne, int nbk) {
    __shared__ int lh[MAXNBK];
    int t = threadIdx.x;
    for (int b = t; b < nbk; b += 256) lh[b] = 0;
    __syncthreads();
    int stride = gridDim.x * 256;
    for (int i = blockIdx.x * 256 + t; i < ne; i += stride)
        atomicAdd(&lh[dst[i] >> 8], 1);
    __syncthreads();
    for (int b = t; b < nbk; b += 256)
        if (lh[b]) atomicAdd(&gbcnt[b], lh[b]);
}

// --- single-block exclusive scan of bucket counts; init bucket cursors ---
__global__ void k_scan_nbk(const int* __restrict__ gbcnt, int* __restrict__ bko,
                           int* __restrict__ gcur, int nbk, int ne) {
    __shared__ int s[MAXNBK];
    int t = threadIdx.x;                       // 512 threads
    int v = (t < nbk) ? gbcnt[t] : 0;
    s[t] = v;
    __syncthreads();
    for (int off = 1; off < MAXNBK; off <<= 1) {
        int a = (t >= off) ? s[t - off] : 0;
        __syncthreads();
        s[t] += a;
        __syncthreads();
    }
    if (t <= nbk) {
        int e = (t < nbk) ? (s[t] - v) : ne;   // exclusive; sentinel at nbk
        bko[t] = e;
        if (t < nbk) gcur[t] = e;
    }
}

// --- partition: edges -> bucket-contiguous staging of packed (dlocal<<20|src) ---
__global__ __launch_bounds__(256) void k_bin(const int* __restrict__ src,
                                             const int* __restrict__ dst,
                                             int* __restrict__ gcur,
                                             unsigned int* __restrict__ staging,
                                             int ne, int nbk) {
    __shared__ int lh[MAXNBK];
    __shared__ int lcur[MAXNBK];
    int t = threadIdx.x;
    for (int b = t; b < nbk; b += 256) lh[b] = 0;
    __syncthreads();
    int stride = gridDim.x * 256;
    for (int i = blockIdx.x * 256 + t; i < ne; i += stride)
        atomicAdd(&lh[dst[i] >> 8], 1);
    __syncthreads();
    for (int b = t; b < nbk; b += 256)
        lcur[b] = lh[b] ? atomicAdd(&gcur[b], lh[b]) : 0;   // reserve block's range
    __syncthreads();
    for (int i = blockIdx.x * 256 + t; i < ne; i += stride) {
        int d = dst[i], s = src[i];
        int p = atomicAdd(&lcur[d >> 8], 1);
        staging[p] = ((unsigned)(d & 255) << 20) | (unsigned)s;
    }
}

// --- per-bucket: LDS count -> scan -> row_start/dinv + LDS-cursor scatter to csr ---
__global__ __launch_bounds__(256) void k_bucket(const unsigned int* __restrict__ staging,
                                                const int* __restrict__ bko,
                                                int* __restrict__ row_start,
                                                int* __restrict__ csr,
                                                float* __restrict__ dinv, int n, int ne) {
    __shared__ int cnt[256];
    __shared__ int scn[256];
    __shared__ int cur[256];
    int b = blockIdx.x, t = threadIdx.x;
    int ebeg = bko[b], eend = bko[b + 1];
    cnt[t] = 0;
    __syncthreads();
    for (int j = ebeg + t; j < eend; j += 256)
        atomicAdd(&cnt[staging[j] >> 20], 1);
    __syncthreads();
    int v = cnt[t];
    scn[t] = v;
    __syncthreads();
    for (int off = 1; off < 256; off <<= 1) {
        int a = (t >= off) ? scn[t - off] : 0;
        __syncthreads();
        scn[t] += a;
        __syncthreads();
    }
    int start = ebeg + scn[t] - v;             // exclusive scan + bucket base
    int node = b * 256 + t;
    if (node <= n) row_start[node] = start;    // node==n lands here when n%256!=0
    if (node < n)  dinv[node] = rsqrtf((float)(v + 1));
    if (b == 0 && t == 0) row_start[n] = ne;   // covers n%256==0 too (same value)
    cur[t] = start;
    __syncthreads();
    for (int j = ebeg + t; j < eend; j += 256) {
        unsigned int e = staging[j];
        int p = atomicAdd(&cur[e >> 20], 1);
        csr[p] = (int)(e & 0xFFFFFu);
    }
}

// --- pull conv1: ax[d] = dinv[d]*(sum_s x[s]*dinv[s] + x[d]*dinv[d]); float4, 4 nbrs/iter ---
__global__ __launch_bounds__(256) void k_pull1(
        const int* __restrict__ row_start, const int* __restrict__ csr,
        const float* __restrict__ dinv, const float4* __restrict__ x4,
        float4* __restrict__ ax4, int n) {
    int t = threadIdx.x;
    int w = t >> 6, lane = t & 63;
    int g = lane >> 4, r = lane & 15;          // 4 neighbor slots x 16 lanes (10 active)
    int d = blockIdx.x * 4 + w;
    if (d >= n) return;
    int beg = row_start[d], end = row_start[d + 1];
    float dd = dinv[d];
    float4 acc = make_float4(0.f, 0.f, 0.f, 0.f);
    if (g == 0 && r < NF4) {                   // self-loop term
        float4 xs = x4[d * NF4 + r];
        acc.x = xs.x * dd; acc.y = xs.y * dd; acc.z = xs.z * dd; acc.w = xs.w * dd;
    }
    for (int j = beg + g; j < end; j += 4) {
        int s = csr[j];
        float wn = dinv[s];
        if (r < NF4) {
            float4 xs = x4[s * NF4 + r];
            acc.x += xs.x * wn; acc.y += xs.y * wn;
            acc.z += xs.z * wn; acc.w += xs.w * wn;
        }
    }
    acc.x += __shfl_xor(acc.x, 16); acc.y += __shfl_xor(acc.y, 16);
    acc.z += __shfl_xor(acc.z, 16); acc.w += __shfl_xor(acc.w, 16);
    acc.x += __shfl_xor(acc.x, 32); acc.y += __shfl_xor(acc.y, 32);
    acc.z += __shfl_xor(acc.z, 32); acc.w += __shfl_xor(acc.w, 32);
    if (g == 0 && r < NF4) {
        float4 o;
        o.x = acc.x * dd; o.y = acc.y * dd; o.z = acc.z * dd; o.w = acc.w * dd;
        ax4[d * NF4 + r] = o;
    }
}

// --- fused per-node MLP: h=relu(ax*W1+b1); spike=(h*Wf+bf>=0.5); s2sp=spike*W2*dinv ---
__global__ __launch_bounds__(256) void k_node(
        const float* __restrict__ ax,
        const float* __restrict__ W1, const float* __restrict__ b1,
        const float* __restrict__ Wf, const float* __restrict__ bf,
        const float* __restrict__ W2, const float* __restrict__ dinv,
        float* __restrict__ s2sp, int n) {
    __shared__ float lW1[NF * H];
    __shared__ float lWf[H * H];
    __shared__ float lW2[H * NC];
    __shared__ float lb1[H];
    __shared__ float lbf[H];
    __shared__ float lax[4][NF];
    __shared__ float lh[4][H];
    int t = threadIdx.x;
    for (int i = t; i < NF * H; i += 256) lW1[i] = W1[i];
    for (int i = t; i < H * H;  i += 256) lWf[i] = Wf[i];
    if (t < H * NC) lW2[t] = W2[t];
    if (t < H) { lb1[t] = b1[t]; lbf[t] = bf[t]; }
    __syncthreads();

    int w = t >> 6, lane = t & 63;
    for (int it = 0; it < 8; ++it) {           // 8 nodes/wave: amortize weight staging
        int node = blockIdx.x * 32 + w * 8 + it;
        if (node >= n) break;

        if (lane < NF) lax[w][lane] = ax[node * NF + lane];
        float acc = lb1[lane];
        #pragma unroll
        for (int k = 0; k < NF; ++k) acc += lax[w][k] * lW1[k * H + lane];
        float h = fmaxf(acc, 0.0f);
        lh[w][lane] = h;

        float mem = lbf[lane];
        #pragma unroll
        for (int k = 0; k < H; ++k) mem += lh[w][k] * lWf[k * H + lane];
        float spike = (mem >= 0.5f) ? 1.0f : 0.0f;

        float v0 = spike * lW2[lane * NC + 0];
        float v1 = spike * lW2[lane * NC + 1];
        float v2 = spike * lW2[lane * NC + 2];
        for (int off = 32; off; off >>= 1) {
            v0 += __shfl_down(v0, off);
            v1 += __shfl_down(v1, off);
            v2 += __shfl_down(v2, off);
        }
        if (lane == 0) {
            float di = dinv[node];
            s2sp[node * 4 + 0] = v0 * di;
            s2sp[node * 4 + 1] = v1 * di;
            s2sp[node * 4 + 2] = v2 * di;
            s2sp[node * 4 + 3] = 0.0f;
        }
    }
}

// --- pull conv2 + bias + filter; one float4 gather per neighbor ---
__global__ __launch_bounds__(256) void k_pull2(
        const int* __restrict__ row_start, const int* __restrict__ csr,
        const float* __restrict__ dinv, const float4* __restrict__ s2sp4,
        const float* __restrict__ b2, const float* __restrict__ ef,
        float* __restrict__ out, int n) {
    int t = threadIdx.x;
    int w = t >> 6, lane = t & 63;
    int d = blockIdx.x * 4 + w;
    if (d >= n) return;
    int beg = row_start[d], end = row_start[d + 1];
    float a0 = 0.f, a1 = 0.f, a2 = 0.f;
    for (int j = beg + lane; j < end; j += 64) {
        float4 v = s2sp4[csr[j]];
        a0 += v.x; a1 += v.y; a2 += v.z;
    }
    for (int off = 32; off; off >>= 1) {
        a0 += __shfl_down(a0, off);
        a1 += __shfl_down(a1, off);
        a2 += __shfl_down(a2, off);
    }
    if (lane == 0) {
        float dd = dinv[d];
        float4 self = s2sp4[d];
        out[d * NC + 0] = (dd * (a0 + self.x) + b2[0]) * ef[0];
        out[d * NC + 1] = (dd * (a1 + self.y) + b2[1]) * ef[1];
        out[d * NC + 2] = (dd * (a2 + self.z) + b2[2]) * ef[2];
    }
}

extern "C" void kernel_launch(void* const* d_in, const int* in_sizes, int n_in,
                              void* d_out, int out_size, void* d_ws, size_t ws_size,
                              hipStream_t stream) {
    const float* x  = (const float*)d_in[0];
    const int*   ei = (const int*)d_in[1];
    const float* W1 = (const float*)d_in[2];
    const float* b1 = (const float*)d_in[3];
    const float* Wf = (const float*)d_in[4];
    const float* bf = (const float*)d_in[5];
    const float* W2 = (const float*)d_in[6];
    const float* b2 = (const float*)d_in[7];
    const float* ef = (const float*)d_in[8];

    int n  = in_sizes[0] / NF;
    int ne = in_sizes[1] / 2;
    const int* src = ei;
    const int* dst = ei + ne;
    int nbk = (n + 255) >> 8;                  // 391

    auto al = [](size_t v) { return (v + 255) & ~(size_t)255; };
    char* ws = (char*)d_ws;
    size_t off = 0;
    // staging (ne u32) and ax (n*NF f32) share: staging dead before ax written
    size_t axsz = (size_t)n * NF * 4, stsz = (size_t)ne * 4;
    unsigned int* staging = (unsigned int*)(ws + off);
    float*        axbuf   = (float*)(ws + off);        off += al(axsz > stsz ? axsz : stsz);
    int*   csr       = (int*)(ws + off);   off += al((size_t)ne * 4);
    float* s2sp      = (float*)(ws + off); off += al((size_t)n * 4 * 4);
    int*   row_start = (int*)(ws + off);   off += al(((size_t)n + 1) * 4);
    float* dinv      = (float*)(ws + off); off += al((size_t)n * 4);
    int*   gbcnt     = (int*)(ws + off);   off += al((size_t)MAXNBK * 4);
    int*   bko       = (int*)(ws + off);   off += al(((size_t)MAXNBK + 1) * 4);
    int*   gcur      = (int*)(ws + off);   off += al((size_t)MAXNBK * 4);
    float* out = (float*)d_out;

    k_zero    <<<2, 256, 0, stream>>>(gbcnt, MAXNBK);
    k_binhist <<<1024, 256, 0, stream>>>(dst, gbcnt, ne, nbk);
    k_scan_nbk<<<1, MAXNBK, 0, stream>>>(gbcnt, bko, gcur, nbk, ne);
    k_bin     <<<1024, 256, 0, stream>>>(src, dst, gcur, staging, ne, nbk);
    k_bucket  <<<nbk, 256, 0, stream>>>(staging, bko, row_start, csr, dinv, n, ne);
    k_pull1   <<<(n + 3) / 4, 256, 0, stream>>>(row_start, csr, dinv,
                                                (const float4*)x, (float4*)axbuf, n);
    k_node    <<<(n + 31) / 32, 256, 0, stream>>>(axbuf, W1, b1, Wf, bf, W2, dinv, s2sp, n);
    k_pull2   <<<(n + 3) / 4, 256, 0, stream>>>(row_start, csr, dinv, (const float4*)s2sp,
                                                b2, ef, out, n);
}